// Round 6
// baseline (97.864 us; speedup 1.0000x reference)
//
#include <hip/hip_runtime.h>
#include <math.h>

#define N_S 2
#define N_V 4
#define DQ  64
#define HH  256
#define WW  320
#define HW  (HH * WW)
#define DPT 16          // depths per thread
#define NDC (DQ / DPT)  // 4
#define WW2 (WW / 2)    // 160 (xy role: 2 px/thread)
#define WW4 (WW / 4)    // 80  (mask role: 4 px/thread)

#define XY_BLOCKS   ((N_S * N_V * NDC * HH * WW2) / 256)   // 5120
#define MASK_BLOCKS ((N_S * N_V * NDC * HH * WW4) / 256)   // 2560
#define TOT_BLOCKS  (XY_BLOCKS + MASK_BLOCKS)              // 7680

typedef float f32x4 __attribute__((ext_vector_type(4)));

// Block-uniform camera algebra: A (3x3), b (3), IK = inv(Kd) (3x3)
__device__ __forceinline__ void camera_setup(
    const float* __restrict__ Kd, const float* __restrict__ Ed,
    const float* __restrict__ Ks, const float* __restrict__ Es,
    int nv, int n, float Am[3][3], float bm[3], float IK[3][3])
{
    // inv(Ed): rigid [R|t] -> [R^T | -R^T t]
    const float* E = Ed + n * 16;
    float Ri[3][3], ti[3];
    #pragma unroll
    for (int r = 0; r < 3; ++r)
        #pragma unroll
        for (int c = 0; c < 3; ++c)
            Ri[r][c] = E[c * 4 + r];
    #pragma unroll
    for (int r = 0; r < 3; ++r)
        ti[r] = -(Ri[r][0] * E[3] + Ri[r][1] * E[7] + Ri[r][2] * E[11]);

    // T = Es @ inv(Ed)
    const float* S = Es + nv * 16;
    float Tr[3][3], Tt[3];
    #pragma unroll
    for (int r = 0; r < 3; ++r) {
        #pragma unroll
        for (int c = 0; c < 3; ++c)
            Tr[r][c] = S[r*4+0]*Ri[0][c] + S[r*4+1]*Ri[1][c] + S[r*4+2]*Ri[2][c];
        Tt[r] = S[r*4+0]*ti[0] + S[r*4+1]*ti[1] + S[r*4+2]*ti[2] + S[r*4+3];
    }

    // A = Ksrc @ Tr ; b = Ksrc @ Tt
    const float* Kv = Ks + nv * 9;
    #pragma unroll
    for (int r = 0; r < 3; ++r) {
        #pragma unroll
        for (int c = 0; c < 3; ++c)
            Am[r][c] = Kv[r*3+0]*Tr[0][c] + Kv[r*3+1]*Tr[1][c] + Kv[r*3+2]*Tr[2][c];
        bm[r] = Kv[r*3+0]*Tt[0] + Kv[r*3+1]*Tt[1] + Kv[r*3+2]*Tt[2];
    }

    // inv(Kd) via adjugate/det
    const float* Km = Kd + n * 9;
    float a=Km[0],b=Km[1],c=Km[2],dd=Km[3],e=Km[4],f=Km[5],g=Km[6],hh=Km[7],k=Km[8];
    float det = a*(e*k - f*hh) - b*(dd*k - f*g) + c*(dd*hh - e*g);
    float inv = 1.0f / det;
    IK[0][0] =  (e*k - f*hh) * inv;
    IK[0][1] = -(b*k - c*hh) * inv;
    IK[0][2] =  (b*f - c*e) * inv;
    IK[1][0] = -(dd*k - f*g) * inv;
    IK[1][1] =  (a*k - c*g) * inv;
    IK[1][2] = -(a*f - c*dd) * inv;
    IK[2][0] =  (dd*hh - e*g) * inv;
    IK[2][1] = -(a*hh - b*g) * inv;
    IK[2][2] =  (a*e - b*dd) * inv;
}

__global__ __launch_bounds__(256) void fused_role_kernel(
    const float* __restrict__ Kd, const float* __restrict__ Ed,
    const float* __restrict__ Ks, const float* __restrict__ Es,
    float* __restrict__ out)
{
    int bid = blockIdx.x;
    // Interleave roles: every 3rd block is a mask block (2560 of 7680),
    // so both streams stay active for the whole dispatch.
    int group = bid / 3;
    int rem   = bid % 3;
    bool is_mask = (rem == 2);
    int role_bid = is_mask ? group : (group * 2 + rem);

    if (!is_mask) {
        // ---------------- xy role: 2 px/thread, one f32x4 stream ----------
        int idx = role_bid * 256 + threadIdx.x;
        int w2 = idx % WW2;
        int tt = idx / WW2;
        int h  = tt % HH;
        tt /= HH;
        int dc = tt % NDC;
        int nv = tt / NDC;
        int n  = nv >> 2;

        float Am[3][3], bm[3], IK[3][3];
        camera_setup(Kd, Ed, Ks, Es, nv, n, Am, bm, IK);
        float b0 = bm[0], b1 = bm[1], b2 = bm[2];

        float X0 = (float)(2 * w2), X1 = X0 + 1.0f, Y = (float)h;
        float rx0 = IK[0][0]*X0 + IK[0][1]*Y + IK[0][2];
        float ry0 = IK[1][0]*X0 + IK[1][1]*Y + IK[1][2];
        float rz0 = IK[2][0]*X0 + IK[2][1]*Y + IK[2][2];
        float rx1 = IK[0][0]*X1 + IK[0][1]*Y + IK[0][2];
        float ry1 = IK[1][0]*X1 + IK[1][1]*Y + IK[1][2];
        float rz1 = IK[2][0]*X1 + IK[2][1]*Y + IK[2][2];

        float bx0 = Am[0][0]*rx0 + Am[0][1]*ry0 + Am[0][2]*rz0;
        float by0 = Am[1][0]*rx0 + Am[1][1]*ry0 + Am[1][2]*rz0;
        float bz0 = Am[2][0]*rx0 + Am[2][1]*ry0 + Am[2][2]*rz0;
        float bx1 = Am[0][0]*rx1 + Am[0][1]*ry1 + Am[0][2]*rz1;
        float by1 = Am[1][0]*rx1 + Am[1][1]*ry1 + Am[1][2]*rz1;
        float bz1 = Am[2][0]*rx1 + Am[2][1]*ry1 + Am[2][2]*rz1;

        size_t pixbase = ((size_t)nv * DQ + (size_t)dc * DPT) * HW
                       + (size_t)h * WW + (size_t)(2 * w2);

        const float step = (float)(9.5 / 63.0);
        int d0 = dc * DPT;

        #pragma unroll
        for (int j = 0; j < DPT; ++j) {
            float depth = 0.5f + (float)(d0 + j) * step;

            float px0 = depth*bx0 + b0, py0 = depth*by0 + b1, pz0 = depth*bz0 + b2;
            float px1 = depth*bx1 + b0, py1 = depth*by1 + b1, pz1 = depth*bz1 + b2;

            float zs0 = (fabsf(pz0) < 1e-8f) ? 1e-8f : pz0;
            float zs1 = (fabsf(pz1) < 1e-8f) ? 1e-8f : pz1;
            float r0 = __builtin_amdgcn_rcpf(zs0); r0 = r0 * (2.0f - zs0 * r0);
            float r1 = __builtin_amdgcn_rcpf(zs1); r1 = r1 * (2.0f - zs1 * r1);

            f32x4 xyv;
            xyv.x = px0 * r0; xyv.y = py0 * r0;
            xyv.z = px1 * r1; xyv.w = py1 * r1;

            size_t p = pixbase + (size_t)j * HW;
            __builtin_nontemporal_store(xyv, (f32x4*)(out + 2 * p));
        }
    } else {
        // ---------------- mask role: 4 px/thread, one f32x4 stream --------
        int idx = role_bid * 256 + threadIdx.x;
        int w4 = idx % WW4;
        int tt = idx / WW4;
        int h  = tt % HH;
        tt /= HH;
        int dc = tt % NDC;
        int nv = tt / NDC;
        int n  = nv >> 2;

        float Am[3][3], bm[3], IK[3][3];
        camera_setup(Kd, Ed, Ks, Es, nv, n, Am, bm, IK);
        float b0 = bm[0], b1 = bm[1], b2 = bm[2];

        float Y = (float)h;
        float bx[4], by[4], bz[4];
        #pragma unroll
        for (int p = 0; p < 4; ++p) {
            float X = (float)(4 * w4 + p);
            float rx = IK[0][0]*X + IK[0][1]*Y + IK[0][2];
            float ry = IK[1][0]*X + IK[1][1]*Y + IK[1][2];
            float rz = IK[2][0]*X + IK[2][1]*Y + IK[2][2];
            bx[p] = Am[0][0]*rx + Am[0][1]*ry + Am[0][2]*rz;
            by[p] = Am[1][0]*rx + Am[1][1]*ry + Am[1][2]*rz;
            bz[p] = Am[2][0]*rx + Am[2][1]*ry + Am[2][2]*rz;
        }

        float* __restrict__ mout = out + (size_t)N_S * N_V * DQ * HW * 2;
        size_t pixbase = ((size_t)nv * DQ + (size_t)dc * DPT) * HW
                       + (size_t)h * WW + (size_t)(4 * w4);

        const float step = (float)(9.5 / 63.0);
        int d0 = dc * DPT;

        #pragma unroll
        for (int j = 0; j < DPT; ++j) {
            float depth = 0.5f + (float)(d0 + j) * step;
            f32x4 mv;
            #pragma unroll
            for (int p = 0; p < 4; ++p) {
                float px = depth*bx[p] + b0;
                float py = depth*by[p] + b1;
                float pz = depth*bz[p] + b2;
                float zs = (fabsf(pz) < 1e-8f) ? 1e-8f : pz;
                float r  = __builtin_amdgcn_rcpf(zs); r = r * (2.0f - zs * r);
                float x = px * r, y = py * r;
                float m = (x >= 0.0f && x <= (float)(WW-1) &&
                           y >= 0.0f && y <= (float)(HH-1) && pz > 0.0f) ? 1.0f : 0.0f;
                mv[p] = m;
            }
            size_t p = pixbase + (size_t)j * HW;
            __builtin_nontemporal_store(mv, (f32x4*)(mout + p));
        }
    }
}

extern "C" void kernel_launch(void* const* d_in, const int* in_sizes, int n_in,
                              void* d_out, int out_size, void* d_ws, size_t ws_size,
                              hipStream_t stream) {
    const float* Kd = (const float*)d_in[0];   // (N,1,3,3)
    const float* Ed = (const float*)d_in[1];   // (N,1,4,4)
    const float* Ks = (const float*)d_in[2];   // (N,V,3,3)
    const float* Es = (const float*)d_in[3];   // (N,V,4,4)

    hipLaunchKernelGGL(fused_role_kernel, dim3(TOT_BLOCKS), dim3(256), 0, stream,
                       Kd, Ed, Ks, Es, (float*)d_out);
}

// Round 7
// 92.539 us; speedup vs baseline: 1.0575x; 1.0575x over previous
//
#include <hip/hip_runtime.h>
#include <math.h>

#define N_S 2
#define N_V 4
#define DQ  64
#define HH  256
#define WW  320
#define HW  (HH * WW)
#define DPT 16          // depths per thread
#define NDC (DQ / DPT)  // 4
#define WW2 (WW / 2)    // 160 (xy kernel: 2 px/thread)
#define WW4 (WW / 4)    // 80  (mask kernel: 4 px/thread)

typedef float f32x4 __attribute__((ext_vector_type(4)));

// Block-uniform camera algebra: A (3x3), b (3), IK = inv(Kd) (3x3)
__device__ __forceinline__ void camera_setup(
    const float* __restrict__ Kd, const float* __restrict__ Ed,
    const float* __restrict__ Ks, const float* __restrict__ Es,
    int nv, int n, float Am[3][3], float bm[3], float IK[3][3])
{
    // inv(Ed): rigid [R|t] -> [R^T | -R^T t]
    const float* E = Ed + n * 16;
    float Ri[3][3], ti[3];
    #pragma unroll
    for (int r = 0; r < 3; ++r)
        #pragma unroll
        for (int c = 0; c < 3; ++c)
            Ri[r][c] = E[c * 4 + r];
    #pragma unroll
    for (int r = 0; r < 3; ++r)
        ti[r] = -(Ri[r][0] * E[3] + Ri[r][1] * E[7] + Ri[r][2] * E[11]);

    // T = Es @ inv(Ed)
    const float* S = Es + nv * 16;
    float Tr[3][3], Tt[3];
    #pragma unroll
    for (int r = 0; r < 3; ++r) {
        #pragma unroll
        for (int c = 0; c < 3; ++c)
            Tr[r][c] = S[r*4+0]*Ri[0][c] + S[r*4+1]*Ri[1][c] + S[r*4+2]*Ri[2][c];
        Tt[r] = S[r*4+0]*ti[0] + S[r*4+1]*ti[1] + S[r*4+2]*ti[2] + S[r*4+3];
    }

    // A = Ksrc @ Tr ; b = Ksrc @ Tt
    const float* Kv = Ks + nv * 9;
    #pragma unroll
    for (int r = 0; r < 3; ++r) {
        #pragma unroll
        for (int c = 0; c < 3; ++c)
            Am[r][c] = Kv[r*3+0]*Tr[0][c] + Kv[r*3+1]*Tr[1][c] + Kv[r*3+2]*Tr[2][c];
        bm[r] = Kv[r*3+0]*Tt[0] + Kv[r*3+1]*Tt[1] + Kv[r*3+2]*Tt[2];
    }

    // inv(Kd) via adjugate/det
    const float* Km = Kd + n * 9;
    float a=Km[0],b=Km[1],c=Km[2],dd=Km[3],e=Km[4],f=Km[5],g=Km[6],hh=Km[7],k=Km[8];
    float det = a*(e*k - f*hh) - b*(dd*k - f*g) + c*(dd*hh - e*g);
    float inv = 1.0f / det;
    IK[0][0] =  (e*k - f*hh) * inv;
    IK[0][1] = -(b*k - c*hh) * inv;
    IK[0][2] =  (b*f - c*e) * inv;
    IK[1][0] = -(dd*k - f*g) * inv;
    IK[1][1] =  (a*k - c*g) * inv;
    IK[1][2] = -(a*f - c*dd) * inv;
    IK[2][0] =  (dd*hh - e*g) * inv;
    IK[2][1] = -(a*hh - b*g) * inv;
    IK[2][2] =  (a*e - b*dd) * inv;
}

// ---------------- xy kernel: 2 px/thread, one f32x4 stream ----------------
__global__ __launch_bounds__(256) void xy_kernel(
    const float* __restrict__ Kd, const float* __restrict__ Ed,
    const float* __restrict__ Ks, const float* __restrict__ Es,
    float* __restrict__ out)
{
    int idx = blockIdx.x * 256 + threadIdx.x;
    int w2 = idx % WW2;
    int tt = idx / WW2;
    int h  = tt % HH;
    tt /= HH;
    int dc = tt % NDC;
    int nv = tt / NDC;
    int n  = nv >> 2;

    float Am[3][3], bm[3], IK[3][3];
    camera_setup(Kd, Ed, Ks, Es, nv, n, Am, bm, IK);
    float b0 = bm[0], b1 = bm[1], b2 = bm[2];

    float X0 = (float)(2 * w2), X1 = X0 + 1.0f, Y = (float)h;
    float rx0 = IK[0][0]*X0 + IK[0][1]*Y + IK[0][2];
    float ry0 = IK[1][0]*X0 + IK[1][1]*Y + IK[1][2];
    float rz0 = IK[2][0]*X0 + IK[2][1]*Y + IK[2][2];
    float rx1 = IK[0][0]*X1 + IK[0][1]*Y + IK[0][2];
    float ry1 = IK[1][0]*X1 + IK[1][1]*Y + IK[1][2];
    float rz1 = IK[2][0]*X1 + IK[2][1]*Y + IK[2][2];

    float bx0 = Am[0][0]*rx0 + Am[0][1]*ry0 + Am[0][2]*rz0;
    float by0 = Am[1][0]*rx0 + Am[1][1]*ry0 + Am[1][2]*rz0;
    float bz0 = Am[2][0]*rx0 + Am[2][1]*ry0 + Am[2][2]*rz0;
    float bx1 = Am[0][0]*rx1 + Am[0][1]*ry1 + Am[0][2]*rz1;
    float by1 = Am[1][0]*rx1 + Am[1][1]*ry1 + Am[1][2]*rz1;
    float bz1 = Am[2][0]*rx1 + Am[2][1]*ry1 + Am[2][2]*rz1;

    size_t pixbase = ((size_t)nv * DQ + (size_t)dc * DPT) * HW
                   + (size_t)h * WW + (size_t)(2 * w2);

    const float step = (float)(9.5 / 63.0);
    int d0 = dc * DPT;

    #pragma unroll
    for (int j = 0; j < DPT; ++j) {
        float depth = 0.5f + (float)(d0 + j) * step;

        float px0 = depth*bx0 + b0, py0 = depth*by0 + b1, pz0 = depth*bz0 + b2;
        float px1 = depth*bx1 + b0, py1 = depth*by1 + b1, pz1 = depth*bz1 + b2;

        float zs0 = (fabsf(pz0) < 1e-8f) ? 1e-8f : pz0;
        float zs1 = (fabsf(pz1) < 1e-8f) ? 1e-8f : pz1;
        float r0 = __builtin_amdgcn_rcpf(zs0); r0 = r0 * (2.0f - zs0 * r0);
        float r1 = __builtin_amdgcn_rcpf(zs1); r1 = r1 * (2.0f - zs1 * r1);

        f32x4 xyv;
        xyv.x = px0 * r0; xyv.y = py0 * r0;
        xyv.z = px1 * r1; xyv.w = py1 * r1;

        size_t p = pixbase + (size_t)j * HW;
        *((f32x4*)(out + 2 * p)) = xyv;   // plain write-back store (no nt)
    }
}

// ---------------- mask kernel: 4 px/thread, one f32x4 stream ----------------
__global__ __launch_bounds__(256) void mask_kernel(
    const float* __restrict__ Kd, const float* __restrict__ Ed,
    const float* __restrict__ Ks, const float* __restrict__ Es,
    float* __restrict__ out)
{
    int idx = blockIdx.x * 256 + threadIdx.x;
    int w4 = idx % WW4;
    int tt = idx / WW4;
    int h  = tt % HH;
    tt /= HH;
    int dc = tt % NDC;
    int nv = tt / NDC;
    int n  = nv >> 2;

    float Am[3][3], bm[3], IK[3][3];
    camera_setup(Kd, Ed, Ks, Es, nv, n, Am, bm, IK);
    float b0 = bm[0], b1 = bm[1], b2 = bm[2];

    float Y = (float)h;
    float bx[4], by[4], bz[4];
    #pragma unroll
    for (int p = 0; p < 4; ++p) {
        float X = (float)(4 * w4 + p);
        float rx = IK[0][0]*X + IK[0][1]*Y + IK[0][2];
        float ry = IK[1][0]*X + IK[1][1]*Y + IK[1][2];
        float rz = IK[2][0]*X + IK[2][1]*Y + IK[2][2];
        bx[p] = Am[0][0]*rx + Am[0][1]*ry + Am[0][2]*rz;
        by[p] = Am[1][0]*rx + Am[1][1]*ry + Am[1][2]*rz;
        bz[p] = Am[2][0]*rx + Am[2][1]*ry + Am[2][2]*rz;
    }

    float* __restrict__ mout = out + (size_t)N_S * N_V * DQ * HW * 2;
    size_t pixbase = ((size_t)nv * DQ + (size_t)dc * DPT) * HW
                   + (size_t)h * WW + (size_t)(4 * w4);

    const float step = (float)(9.5 / 63.0);
    int d0 = dc * DPT;

    #pragma unroll
    for (int j = 0; j < DPT; ++j) {
        float depth = 0.5f + (float)(d0 + j) * step;
        f32x4 mv;
        #pragma unroll
        for (int p = 0; p < 4; ++p) {
            float px = depth*bx[p] + b0;
            float py = depth*by[p] + b1;
            float pz = depth*bz[p] + b2;
            float zs = (fabsf(pz) < 1e-8f) ? 1e-8f : pz;
            float r  = __builtin_amdgcn_rcpf(zs); r = r * (2.0f - zs * r);
            float x = px * r, y = py * r;
            float m = (x >= 0.0f && x <= (float)(WW-1) &&
                       y >= 0.0f && y <= (float)(HH-1) && pz > 0.0f) ? 1.0f : 0.0f;
            mv[p] = m;
        }
        size_t p = pixbase + (size_t)j * HW;
        *((f32x4*)(mout + p)) = mv;       // plain write-back store (no nt)
    }
}

extern "C" void kernel_launch(void* const* d_in, const int* in_sizes, int n_in,
                              void* d_out, int out_size, void* d_ws, size_t ws_size,
                              hipStream_t stream) {
    const float* Kd = (const float*)d_in[0];   // (N,1,3,3)
    const float* Ed = (const float*)d_in[1];   // (N,1,4,4)
    const float* Ks = (const float*)d_in[2];   // (N,V,3,3)
    const float* Es = (const float*)d_in[3];   // (N,V,4,4)
    float* out = (float*)d_out;

    int xy_blocks   = (N_S * N_V * NDC * HH * WW2) / 256;  // 5120
    int mask_blocks = (N_S * N_V * NDC * HH * WW4) / 256;  // 2560

    hipLaunchKernelGGL(xy_kernel,   dim3(xy_blocks),   dim3(256), 0, stream,
                       Kd, Ed, Ks, Es, out);
    hipLaunchKernelGGL(mask_kernel, dim3(mask_blocks), dim3(256), 0, stream,
                       Kd, Ed, Ks, Es, out);
}

// Round 8
// 91.587 us; speedup vs baseline: 1.0685x; 1.0104x over previous
//
#include <hip/hip_runtime.h>
#include <math.h>

#define N_S 2
#define N_V 4
#define DQ  64
#define HH  256
#define WW  320
#define HW  (HH * WW)
#define DPT 16          // depths per thread
#define NDC (DQ / DPT)  // 4
#define WW2 (WW / 2)    // 160 (xy role: 2 px/thread)
#define WW4 (WW / 4)    // 80  (mask role: 4 px/thread)

#define XY_BLOCKS   ((N_S * N_V * NDC * HH * WW2) / 256)   // 5120
#define MASK_BLOCKS ((N_S * N_V * NDC * HH * WW4) / 256)   // 2560
#define TOT_BLOCKS  (XY_BLOCKS + MASK_BLOCKS)              // 7680

typedef float f32x4 __attribute__((ext_vector_type(4)));

// Block-uniform camera algebra: A (3x3), b (3), IK = inv(Kd) (3x3)
__device__ __forceinline__ void camera_setup(
    const float* __restrict__ Kd, const float* __restrict__ Ed,
    const float* __restrict__ Ks, const float* __restrict__ Es,
    int nv, int n, float Am[3][3], float bm[3], float IK[3][3])
{
    // inv(Ed): rigid [R|t] -> [R^T | -R^T t]
    const float* E = Ed + n * 16;
    float Ri[3][3], ti[3];
    #pragma unroll
    for (int r = 0; r < 3; ++r)
        #pragma unroll
        for (int c = 0; c < 3; ++c)
            Ri[r][c] = E[c * 4 + r];
    #pragma unroll
    for (int r = 0; r < 3; ++r)
        ti[r] = -(Ri[r][0] * E[3] + Ri[r][1] * E[7] + Ri[r][2] * E[11]);

    // T = Es @ inv(Ed)
    const float* S = Es + nv * 16;
    float Tr[3][3], Tt[3];
    #pragma unroll
    for (int r = 0; r < 3; ++r) {
        #pragma unroll
        for (int c = 0; c < 3; ++c)
            Tr[r][c] = S[r*4+0]*Ri[0][c] + S[r*4+1]*Ri[1][c] + S[r*4+2]*Ri[2][c];
        Tt[r] = S[r*4+0]*ti[0] + S[r*4+1]*ti[1] + S[r*4+2]*ti[2] + S[r*4+3];
    }

    // A = Ksrc @ Tr ; b = Ksrc @ Tt
    const float* Kv = Ks + nv * 9;
    #pragma unroll
    for (int r = 0; r < 3; ++r) {
        #pragma unroll
        for (int c = 0; c < 3; ++c)
            Am[r][c] = Kv[r*3+0]*Tr[0][c] + Kv[r*3+1]*Tr[1][c] + Kv[r*3+2]*Tr[2][c];
        bm[r] = Kv[r*3+0]*Tt[0] + Kv[r*3+1]*Tt[1] + Kv[r*3+2]*Tt[2];
    }

    // inv(Kd) via adjugate/det
    const float* Km = Kd + n * 9;
    float a=Km[0],b=Km[1],c=Km[2],dd=Km[3],e=Km[4],f=Km[5],g=Km[6],hh=Km[7],k=Km[8];
    float det = a*(e*k - f*hh) - b*(dd*k - f*g) + c*(dd*hh - e*g);
    float inv = 1.0f / det;
    IK[0][0] =  (e*k - f*hh) * inv;
    IK[0][1] = -(b*k - c*hh) * inv;
    IK[0][2] =  (b*f - c*e) * inv;
    IK[1][0] = -(dd*k - f*g) * inv;
    IK[1][1] =  (a*k - c*g) * inv;
    IK[1][2] = -(a*f - c*dd) * inv;
    IK[2][0] =  (dd*hh - e*g) * inv;
    IK[2][1] = -(a*hh - b*g) * inv;
    IK[2][2] =  (a*e - b*dd) * inv;
}

__global__ __launch_bounds__(256) void fused_seq_kernel(
    const float* __restrict__ Kd, const float* __restrict__ Ed,
    const float* __restrict__ Ks, const float* __restrict__ Es,
    float* __restrict__ out)
{
    int bid = blockIdx.x;

    if (bid < XY_BLOCKS) {
        // ---------------- xy role: 2 px/thread, one f32x4 stream ----------
        int idx = bid * 256 + threadIdx.x;
        int w2 = idx % WW2;
        int tt = idx / WW2;
        int h  = tt % HH;
        tt /= HH;
        int dc = tt % NDC;
        int nv = tt / NDC;
        int n  = nv >> 2;

        float Am[3][3], bm[3], IK[3][3];
        camera_setup(Kd, Ed, Ks, Es, nv, n, Am, bm, IK);
        float b0 = bm[0], b1 = bm[1], b2 = bm[2];

        float X0 = (float)(2 * w2), X1 = X0 + 1.0f, Y = (float)h;
        float rx0 = IK[0][0]*X0 + IK[0][1]*Y + IK[0][2];
        float ry0 = IK[1][0]*X0 + IK[1][1]*Y + IK[1][2];
        float rz0 = IK[2][0]*X0 + IK[2][1]*Y + IK[2][2];
        float rx1 = IK[0][0]*X1 + IK[0][1]*Y + IK[0][2];
        float ry1 = IK[1][0]*X1 + IK[1][1]*Y + IK[1][2];
        float rz1 = IK[2][0]*X1 + IK[2][1]*Y + IK[2][2];

        float bx0 = Am[0][0]*rx0 + Am[0][1]*ry0 + Am[0][2]*rz0;
        float by0 = Am[1][0]*rx0 + Am[1][1]*ry0 + Am[1][2]*rz0;
        float bz0 = Am[2][0]*rx0 + Am[2][1]*ry0 + Am[2][2]*rz0;
        float bx1 = Am[0][0]*rx1 + Am[0][1]*ry1 + Am[0][2]*rz1;
        float by1 = Am[1][0]*rx1 + Am[1][1]*ry1 + Am[1][2]*rz1;
        float bz1 = Am[2][0]*rx1 + Am[2][1]*ry1 + Am[2][2]*rz1;

        size_t pixbase = ((size_t)nv * DQ + (size_t)dc * DPT) * HW
                       + (size_t)h * WW + (size_t)(2 * w2);

        const float step = (float)(9.5 / 63.0);
        int d0 = dc * DPT;

        #pragma unroll
        for (int j = 0; j < DPT; ++j) {
            float depth = 0.5f + (float)(d0 + j) * step;

            float px0 = depth*bx0 + b0, py0 = depth*by0 + b1, pz0 = depth*bz0 + b2;
            float px1 = depth*bx1 + b0, py1 = depth*by1 + b1, pz1 = depth*bz1 + b2;

            float zs0 = (fabsf(pz0) < 1e-8f) ? 1e-8f : pz0;
            float zs1 = (fabsf(pz1) < 1e-8f) ? 1e-8f : pz1;
            float r0 = __builtin_amdgcn_rcpf(zs0); r0 = r0 * (2.0f - zs0 * r0);
            float r1 = __builtin_amdgcn_rcpf(zs1); r1 = r1 * (2.0f - zs1 * r1);

            f32x4 xyv;
            xyv.x = px0 * r0; xyv.y = py0 * r0;
            xyv.z = px1 * r1; xyv.w = py1 * r1;

            size_t p = pixbase + (size_t)j * HW;
            __builtin_nontemporal_store(xyv, (f32x4*)(out + 2 * p));
        }
    } else {
        // ---------------- mask role: 4 px/thread, one f32x4 stream --------
        int idx = (bid - XY_BLOCKS) * 256 + threadIdx.x;
        int w4 = idx % WW4;
        int tt = idx / WW4;
        int h  = tt % HH;
        tt /= HH;
        int dc = tt % NDC;
        int nv = tt / NDC;
        int n  = nv >> 2;

        float Am[3][3], bm[3], IK[3][3];
        camera_setup(Kd, Ed, Ks, Es, nv, n, Am, bm, IK);
        float b0 = bm[0], b1 = bm[1], b2 = bm[2];

        float Y = (float)h;
        float bx[4], by[4], bz[4];
        #pragma unroll
        for (int p = 0; p < 4; ++p) {
            float X = (float)(4 * w4 + p);
            float rx = IK[0][0]*X + IK[0][1]*Y + IK[0][2];
            float ry = IK[1][0]*X + IK[1][1]*Y + IK[1][2];
            float rz = IK[2][0]*X + IK[2][1]*Y + IK[2][2];
            bx[p] = Am[0][0]*rx + Am[0][1]*ry + Am[0][2]*rz;
            by[p] = Am[1][0]*rx + Am[1][1]*ry + Am[1][2]*rz;
            bz[p] = Am[2][0]*rx + Am[2][1]*ry + Am[2][2]*rz;
        }

        float* __restrict__ mout = out + (size_t)N_S * N_V * DQ * HW * 2;
        size_t pixbase = ((size_t)nv * DQ + (size_t)dc * DPT) * HW
                       + (size_t)h * WW + (size_t)(4 * w4);

        const float step = (float)(9.5 / 63.0);
        int d0 = dc * DPT;

        #pragma unroll
        for (int j = 0; j < DPT; ++j) {
            float depth = 0.5f + (float)(d0 + j) * step;
            f32x4 mv;
            #pragma unroll
            for (int p = 0; p < 4; ++p) {
                float px = depth*bx[p] + b0;
                float py = depth*by[p] + b1;
                float pz = depth*bz[p] + b2;
                float zs = (fabsf(pz) < 1e-8f) ? 1e-8f : pz;
                float r  = __builtin_amdgcn_rcpf(zs); r = r * (2.0f - zs * r);
                float x = px * r, y = py * r;
                float m = (x >= 0.0f && x <= (float)(WW-1) &&
                           y >= 0.0f && y <= (float)(HH-1) && pz > 0.0f) ? 1.0f : 0.0f;
                mv[p] = m;
            }
            size_t p = pixbase + (size_t)j * HW;
            __builtin_nontemporal_store(mv, (f32x4*)(mout + p));
        }
    }
}

extern "C" void kernel_launch(void* const* d_in, const int* in_sizes, int n_in,
                              void* d_out, int out_size, void* d_ws, size_t ws_size,
                              hipStream_t stream) {
    const float* Kd = (const float*)d_in[0];   // (N,1,3,3)
    const float* Ed = (const float*)d_in[1];   // (N,1,4,4)
    const float* Ks = (const float*)d_in[2];   // (N,V,3,3)
    const float* Es = (const float*)d_in[3];   // (N,V,4,4)

    hipLaunchKernelGGL(fused_seq_kernel, dim3(TOT_BLOCKS), dim3(256), 0, stream,
                       Kd, Ed, Ks, Es, (float*)d_out);
}